// Round 4
// baseline (73.189 us; speedup 1.0000x reference)
//
#include <hip/hip_runtime.h>

// Problem constants: B=4, N=512, M=512, D=128, H=256, DOUT=128
#define BB    4
#define NN    512
#define MM    512
#define DD    128
#define HH    256
#define DOUTC 128
#define NTILE 16               // n-rows per abs_sum block
#define MSPLIT 4
#define MCHUNK (MM / MSPLIT)   // 128

typedef float v2f __attribute__((ext_vector_type(2)));

// ---------------------------------------------------------------------------
// Kernel 1: precompute (516 blocks x 256 threads)
// Blocks 0..255:   A[b,m,h]  = Y[b,m]·W1[0:D,h]            (rows 0..2047 of AC)
// Blocks 256..511: C[b,n,h]  = X[b,n]·W1[D:2D,h] + b1[h]   (rows 2048..4095)
// Blocks 512..515: SAt[b,h]  = (sum_m Y[b,m])·W1[0:D,h]    (linearity of sum)
// Main blocks: 8 rows staged in LDS (broadcast ds_read_b128), thread =
// (h-pair, row-half), float2 packed FMA. Unroll capped (round-1 spill lesson).
// ---------------------------------------------------------------------------
__global__ __launch_bounds__(256) void precompute_ac(
    const float* __restrict__ X, const float* __restrict__ Y,
    const float* __restrict__ W1, const float* __restrict__ b1,
    float* __restrict__ AC, float* __restrict__ SAt)
{
    __shared__ __align__(16) float rows[8][DD];   // 4 KB
    const int bid = blockIdx.x;
    const int t   = threadIdx.x;

    if (bid < 512) {
        const int isC = bid >> 8;
        const int r0  = (bid & 255) * 8;          // global row (b*512 + m)
        const float* src = isC ? X : Y;

        // stage 8 rows (1024 floats = 256 float4)
        const float4* s4 = reinterpret_cast<const float4*>(src + (size_t)r0 * DD);
        reinterpret_cast<float4*>(&rows[0][0])[t] = s4[t];
        __syncthreads();

        const int h0 = (t & 127) * 2;
        const int rh = (t >> 7) * 4;              // wave-uniform row group

        v2f acc[4] = {(v2f){0.f,0.f}, (v2f){0.f,0.f}, (v2f){0.f,0.f}, (v2f){0.f,0.f}};
        const float* wp = W1 + (isC ? DD * HH : 0) + h0;

#pragma unroll 2
        for (int dg = 0; dg < DD; dg += 4) {
            v2f w[4];
#pragma unroll
            for (int d = 0; d < 4; ++d)
                w[d] = *reinterpret_cast<const v2f*>(&wp[(dg + d) * HH]);
#pragma unroll
            for (int j = 0; j < 4; ++j) {
                const float4 rv = *reinterpret_cast<const float4*>(&rows[rh + j][dg]);
                acc[j] += w[0] * (v2f){rv.x, rv.x};
                acc[j] += w[1] * (v2f){rv.y, rv.y};
                acc[j] += w[2] * (v2f){rv.z, rv.z};
                acc[j] += w[3] * (v2f){rv.w, rv.w};
            }
        }

        v2f bias = (v2f){0.f, 0.f};
        if (isC) bias = *reinterpret_cast<const v2f*>(&b1[h0]);
#pragma unroll
        for (int j = 0; j < 4; ++j) {
            v2f o = acc[j] + bias;
            *reinterpret_cast<v2f*>(
                &AC[((size_t)(isC * 2048 + r0 + rh + j)) * HH + h0]) = o;
        }
    } else {
        // SAt blocks: b = bid-512
        const int b = bid - 512;
        const int d    = t & 127;
        const int half = t >> 7;
        float s = 0.f;
        const float* yp = Y + ((size_t)(b * MM + half * 256)) * DD + d;
#pragma unroll 4
        for (int i = 0; i < 256; ++i)
            s += yp[(size_t)i * DD];
        rows[half][d] = s;
        __syncthreads();
        if (t < 128) rows[0][t] += rows[1][t];
        __syncthreads();

        const int h = t;
        float sat = 0.f;
#pragma unroll 4
        for (int d2 = 0; d2 < DD; ++d2)
            sat = fmaf(rows[0][d2], W1[d2 * HH + h], sat);   // rows[0][d2] broadcast
        SAt[b * HH + h] = sat;
    }
}

// ---------------------------------------------------------------------------
// Kernel 2: abs-sum main loop (1.5 VALU instr/elem via relu(x)=(x+|x|)/2)
//   part[b,n,ms,h] = sum_{m in chunk} |A[b,m,h] + C[b,n,h]|
// grid = 4*32*4 = 512 blocks x 256 threads (2 blocks/CU).
// Thread = (h-pair, n-half): 2 h x 8 n = 16 elems per m-iter.
// ---------------------------------------------------------------------------
__global__ __launch_bounds__(256) void abs_sum(
    const float* __restrict__ A, const float* __restrict__ C,
    float* __restrict__ part)
{
    const int bid = blockIdx.x;
    const int ms = bid & (MSPLIT - 1);
    const int nt = (bid >> 2) & 31;
    const int b  = bid >> 7;
    const int t  = threadIdx.x;
    const int h0 = (t & 127) * 2;
    const int nh = t >> 7;                       // wave-uniform
    const int n0 = nt * NTILE + nh * 8;

    v2f c[8], acc[8];
#pragma unroll
    for (int i = 0; i < 8; ++i) {
        c[i] = *reinterpret_cast<const v2f*>(&C[((size_t)(b * NN + n0 + i)) * HH + h0]);
        acc[i] = (v2f){0.f, 0.f};
    }

    const float* Ab = A + ((size_t)(b * MM + ms * MCHUNK)) * HH + h0;
#pragma unroll 4
    for (int m = 0; m < MCHUNK; ++m) {
        const v2f a2 = *reinterpret_cast<const v2f*>(&Ab[(size_t)m * HH]);
#pragma unroll
        for (int i = 0; i < 8; ++i) {
            const v2f s = a2 + c[i];             // v_pk_add_f32
            acc[i].x += fabsf(s.x);              // v_add_f32 acc, |s|, acc
            acc[i].y += fabsf(s.y);
        }
    }

#pragma unroll
    for (int i = 0; i < 8; ++i)
        *reinterpret_cast<v2f*>(
            &part[(((size_t)(b * NN + n0 + i)) * MSPLIT + ms) * HH + h0]) = acc[i];
}

// ---------------------------------------------------------------------------
// Kernel 3: finalize (512 blocks x 256 threads, 4 bn-rows/block)
//   S[r,h]   = 0.5*( SAt[b,h] + 512*C[bn,h] + sum_ms part[bn,ms,h] )
//   out[bn,o]= sum_h S[r,h]*W2[h,o] + 512*b2[o]
// ---------------------------------------------------------------------------
__global__ __launch_bounds__(256) void finalize(
    const float* __restrict__ part, const float* __restrict__ SAt,
    const float* __restrict__ C, const float* __restrict__ W2,
    const float* __restrict__ b2, float* __restrict__ out)
{
    __shared__ __align__(16) float S[4][HH];   // 4 KB
    const int bn0 = blockIdx.x * 4;
    const int b   = bn0 >> 9;
    const int t   = threadIdx.x;               // = h

    const float sat = SAt[b * HH + t];
#pragma unroll
    for (int r = 0; r < 4; ++r) {
        float ab = 0.f;
#pragma unroll
        for (int ms = 0; ms < MSPLIT; ++ms)
            ab += part[((size_t)(bn0 + r) * MSPLIT + ms) * HH + t];
        S[r][t] = 0.5f * (sat + 512.f * C[(size_t)(bn0 + r) * HH + t] + ab);
    }
    __syncthreads();

    const int o0 = (t & 63) * 2;
    const int r  = t >> 6;                     // wave-uniform

    v2f acc2 = *reinterpret_cast<const v2f*>(&b2[o0]);
    acc2 *= 512.f;

    const float* w2p = W2 + o0;
#pragma unroll 4
    for (int k = 0; k < HH; ++k) {
        const v2f w2v = *reinterpret_cast<const v2f*>(&w2p[k * DOUTC]);  // coalesced
        const float sv = S[r][k];                                        // broadcast
        acc2 += w2v * (v2f){sv, sv};
    }

    *reinterpret_cast<v2f*>(&out[(size_t)(bn0 + r) * DOUTC + o0]) = acc2;
}

// ---------------------------------------------------------------------------
extern "C" void kernel_launch(void* const* d_in, const int* in_sizes, int n_in,
                              void* d_out, int out_size, void* d_ws, size_t ws_size,
                              hipStream_t stream) {
    const float* X  = (const float*)d_in[0];
    const float* Y  = (const float*)d_in[1];
    const float* W1 = (const float*)d_in[2];
    const float* b1 = (const float*)d_in[3];
    const float* W2 = (const float*)d_in[4];
    const float* b2 = (const float*)d_in[5];
    float* out = (float*)d_out;

    float* AC   = (float*)d_ws;                           // 4 MB
    float* A    = AC;                                     // rows 0..2047
    float* C    = AC + 2048 * HH;                         // rows 2048..4095
    float* part = AC + 4096 * HH;                         // 8 MB
    float* SAt  = part + (size_t)BB * NN * MSPLIT * HH;   // 4 KB

    hipLaunchKernelGGL(precompute_ac, dim3(516), dim3(256), 0, stream,
                       X, Y, W1, b1, AC, SAt);
    hipLaunchKernelGGL(abs_sum, dim3(512), dim3(256), 0, stream,
                       A, C, part);
    hipLaunchKernelGGL(finalize, dim3(512), dim3(256), 0, stream,
                       part, SAt, C, W2, b2, out);
}

// Round 5
// 54.354 us; speedup vs baseline: 1.3465x; 1.3465x over previous
//
#include <hip/hip_runtime.h>

// Problem constants: B=4, N=512, M=512, D=128, H=256, DOUT=128
#define BB    4
#define NN    512
#define MM    512
#define DD    128
#define HH    256
#define DOUTC 128

typedef float v2f __attribute__((ext_vector_type(2)));
typedef float v4f __attribute__((ext_vector_type(4)));

// ---------------------------------------------------------------------------
// Kernel 1: precompute (256 blocks x 512 threads, 16 rows/block)
// Blocks 0..127:   A rows  (from Y, W1[0:D])      -> AC rows 0..2047
// Blocks 128..255: C rows  (from X, W1[D:2D]+b1)  -> AC rows 2048..4095
// Thread = (h-quad, row-pair): per dg(4 d): 4 float4 W1 loads + 2 broadcast
// ds_read_b128 + 16 v_pk_fma_f32. Unroll capped at 2 (round-1 spill lesson).
// ---------------------------------------------------------------------------
__global__ __launch_bounds__(512) void precompute_ac(
    const float* __restrict__ X, const float* __restrict__ Y,
    const float* __restrict__ W1, const float* __restrict__ b1,
    float* __restrict__ AC)
{
    __shared__ __align__(16) float rows16[16][DD];   // 8 KB
    const int bid = blockIdx.x;
    const int t   = threadIdx.x;
    const int isC = bid >> 7;
    const int r0  = (bid & 127) * 16;                // global row (b*512+m)
    const float* src = isC ? X : Y;

    // stage 16 rows = 2048 floats = 512 float4 (1 per thread, coalesced)
    reinterpret_cast<v4f*>(&rows16[0][0])[t] =
        reinterpret_cast<const v4f*>(src + (size_t)r0 * DD)[t];
    __syncthreads();

    const int h0 = (t & 63) * 4;      // h-quad
    const int rp = t >> 6;            // 0..7 -> rows rp*2, rp*2+1 (wave-uniform)

    v2f accA[2] = {(v2f){0.f,0.f}, (v2f){0.f,0.f}};  // row rp*2
    v2f accB[2] = {(v2f){0.f,0.f}, (v2f){0.f,0.f}};  // row rp*2+1
    const float* wp = W1 + (isC ? DD * HH : 0) + h0;

#pragma unroll 2
    for (int dg = 0; dg < DD; dg += 4) {
        v4f w[4];
#pragma unroll
        for (int d = 0; d < 4; ++d)
            w[d] = *reinterpret_cast<const v4f*>(&wp[(dg + d) * HH]);
        const v4f ra = *reinterpret_cast<const v4f*>(&rows16[rp * 2 + 0][dg]);
        const v4f rb = *reinterpret_cast<const v4f*>(&rows16[rp * 2 + 1][dg]);
#pragma unroll
        for (int d = 0; d < 4; ++d) {
            accA[0] += (v2f){w[d].x, w[d].y} * ra[d];
            accA[1] += (v2f){w[d].z, w[d].w} * ra[d];
            accB[0] += (v2f){w[d].x, w[d].y} * rb[d];
            accB[1] += (v2f){w[d].z, w[d].w} * rb[d];
        }
    }

    v4f bias = (v4f){0.f, 0.f, 0.f, 0.f};
    if (isC) bias = *reinterpret_cast<const v4f*>(&b1[h0]);

    v4f oA = (v4f){accA[0].x, accA[0].y, accA[1].x, accA[1].y} + bias;
    v4f oB = (v4f){accB[0].x, accB[0].y, accB[1].x, accB[1].y} + bias;
    float* dst = AC + ((size_t)(isC * 2048 + r0 + rp * 2)) * HH + h0;
    *reinterpret_cast<v4f*>(dst)      = oA;
    *reinterpret_cast<v4f*>(dst + HH) = oB;
}

// ---------------------------------------------------------------------------
// Kernel 2: fused abs-sum + W2 epilogue (256 blocks x 512 threads)
// Block = (b, nt): owns 8 n-rows, streams ALL 512 m-rows of A[b] once.
//   phase A: acc[r] = sum_m |A+C|, sat = sum_m A   (relu = (x+|x|)/2)
//   phase B: S[r][h] = 0.5*(sat + 512*C + acc) in LDS
//   phase C: out[bn,:] = S·W2 + 512*b2 (k-split GEMM, LDS reduce)
// ---------------------------------------------------------------------------
__global__ __launch_bounds__(512) void fused_main(
    const float* __restrict__ A, const float* __restrict__ C,
    const float* __restrict__ W2, const float* __restrict__ b2,
    float* __restrict__ out)
{
    __shared__ __align__(16) float S[8][HH];   // 8 KB
    __shared__ __align__(16) v4f red[256];     // 4 KB
    const int bid = blockIdx.x;
    const int b   = bid >> 6;
    const int n0  = (bid & 63) * 8;
    const int t   = threadIdx.x;

    // ---- phase A: thread = (h-pair, n-group of 2 rows) ----
    const int h0  = (t & 127) * 2;
    const int ng  = t >> 7;                    // 0..3 (wave-uniform)
    const int n0g = n0 + ng * 2;

    v2f c0 = *reinterpret_cast<const v2f*>(&C[((size_t)(b * NN + n0g + 0)) * HH + h0]);
    v2f c1 = *reinterpret_cast<const v2f*>(&C[((size_t)(b * NN + n0g + 1)) * HH + h0]);
    v2f acc0 = (v2f){0.f,0.f}, acc1 = (v2f){0.f,0.f}, sat = (v2f){0.f,0.f};

    const float* Ab = A + ((size_t)(b * MM)) * HH + h0;
#pragma unroll 8
    for (int m = 0; m < MM; ++m) {
        const v2f a2 = *reinterpret_cast<const v2f*>(&Ab[(size_t)m * HH]);
        sat += a2;                              // v_pk_add_f32
        const v2f s0 = a2 + c0;                 // v_pk_add_f32
        const v2f s1 = a2 + c1;
        acc0.x += fabsf(s0.x);                  // v_add_f32 acc, |s|, acc
        acc0.y += fabsf(s0.y);
        acc1.x += fabsf(s1.x);
        acc1.y += fabsf(s1.y);
    }

    const v2f S0 = 0.5f * (sat + 512.f * c0 + acc0);
    const v2f S1 = 0.5f * (sat + 512.f * c1 + acc1);
    *reinterpret_cast<v2f*>(&S[ng * 2 + 0][h0]) = S0;
    *reinterpret_cast<v2f*>(&S[ng * 2 + 1][h0]) = S1;
    __syncthreads();

    // ---- phase C: thread = (o-quad, row, k-half) ----
    const int o0 = (t & 31) * 4;
    const int r  = (t >> 5) & 7;
    const int kh = t >> 8;                     // 0 or 1
    const int k0 = kh * 128;

    v4f a4 = (v4f){0.f, 0.f, 0.f, 0.f};
    const float* w2p = W2 + o0;
#pragma unroll 4
    for (int k = 0; k < 128; k += 2) {
        const v2f sv = *reinterpret_cast<const v2f*>(&S[r][k0 + k]);
        const v4f wA = *reinterpret_cast<const v4f*>(&w2p[(k0 + k) * DOUTC]);
        const v4f wB = *reinterpret_cast<const v4f*>(&w2p[(k0 + k + 1) * DOUTC]);
        a4 += wA * sv.x;                       // 2x v_pk_fma_f32
        a4 += wB * sv.y;
    }

    if (kh) red[t & 255] = a4;
    __syncthreads();
    if (!kh) {
        v4f o = a4 + red[t];
        o += 512.f * (*reinterpret_cast<const v4f*>(&b2[o0]));
        *reinterpret_cast<v4f*>(&out[((size_t)(b * NN + n0 + r)) * DOUTC + o0]) = o;
    }
}

// ---------------------------------------------------------------------------
extern "C" void kernel_launch(void* const* d_in, const int* in_sizes, int n_in,
                              void* d_out, int out_size, void* d_ws, size_t ws_size,
                              hipStream_t stream) {
    const float* X  = (const float*)d_in[0];
    const float* Y  = (const float*)d_in[1];
    const float* W1 = (const float*)d_in[2];
    const float* b1 = (const float*)d_in[3];
    const float* W2 = (const float*)d_in[4];
    const float* b2 = (const float*)d_in[5];
    float* out = (float*)d_out;

    float* AC = (float*)d_ws;        // 4 MB: A rows 0..2047, C rows 2048..4095
    float* A  = AC;
    float* Cm = AC + 2048 * HH;

    hipLaunchKernelGGL(precompute_ac, dim3(256), dim3(512), 0, stream,
                       X, Y, W1, b1, AC);
    hipLaunchKernelGGL(fused_main, dim3(256), dim3(512), 0, stream,
                       A, Cm, W2, b2, out);
}

// Round 6
// 51.260 us; speedup vs baseline: 1.4278x; 1.0604x over previous
//
#include <hip/hip_runtime.h>

// Problem constants: B=4, N=512, M=512, D=128, H=256, DOUT=128
#define BB    4
#define NN    512
#define MM    512
#define DD    128
#define HH    256
#define DOUTC 128

typedef float v2f __attribute__((ext_vector_type(2)));
typedef float v4f __attribute__((ext_vector_type(4)));

// ---------------------------------------------------------------------------
// Kernel 1: precompute (256 blocks x 1024 threads = 16 waves/CU)
// Blocks 0..127:   A rows (from Y, W1[0:D])       -> AC rows 0..2047
// Blocks 128..255: C rows (from X, W1[D:2D]+b1)   -> AC rows 2048..4095
// Thread = (h-quad hq=t&63, row r=t>>6 of 16). Per d-group: 1 broadcast
// ds_read_b128 + 4x W1 dwordx4 (L1-hit across the 16 row-groups) + 8 pk_fma.
// ---------------------------------------------------------------------------
__global__ __launch_bounds__(1024) void precompute_ac(
    const float* __restrict__ X, const float* __restrict__ Y,
    const float* __restrict__ W1, const float* __restrict__ b1,
    float* __restrict__ AC)
{
    __shared__ __align__(16) float rows16[16][DD];   // 8 KB
    const int bid = blockIdx.x;
    const int t   = threadIdx.x;
    const int isC = bid >> 7;
    const int r0  = (bid & 127) * 16;                // global row (b*512+m)
    const float* src = isC ? X : Y;

    if (t < 512)
        reinterpret_cast<v4f*>(&rows16[0][0])[t] =
            reinterpret_cast<const v4f*>(src + (size_t)r0 * DD)[t];
    __syncthreads();

    const int hq = t & 63, h0 = hq * 4;
    const int r  = t >> 6;                           // wave-uniform row
    const float* wp = W1 + (isC ? DD * HH : 0) + h0;

    v4f acc = (v4f){0.f, 0.f, 0.f, 0.f};
#pragma unroll 2
    for (int dg = 0; dg < DD; dg += 4) {
        const v4f rv = *reinterpret_cast<const v4f*>(&rows16[r][dg]);  // broadcast
        const v4f w0 = *reinterpret_cast<const v4f*>(&wp[(dg + 0) * HH]);
        const v4f w1 = *reinterpret_cast<const v4f*>(&wp[(dg + 1) * HH]);
        const v4f w2 = *reinterpret_cast<const v4f*>(&wp[(dg + 2) * HH]);
        const v4f w3 = *reinterpret_cast<const v4f*>(&wp[(dg + 3) * HH]);
        acc += w0 * rv.x;
        acc += w1 * rv.y;
        acc += w2 * rv.z;
        acc += w3 * rv.w;
    }

    if (isC) acc += *reinterpret_cast<const v4f*>(&b1[h0]);
    *reinterpret_cast<v4f*>(&AC[((size_t)(isC * 2048 + r0 + r)) * HH + h0]) = acc;
}

// ---------------------------------------------------------------------------
// Kernel 2: fused abs-sum + W2 epilogue (256 blocks x 1024 threads)
// Block = (b, nt): 8 n-rows. Thread = (hq=t&63 -> 4 h, ng=(t>>6)&3 -> 2 n-rows,
// qm=t>>8 -> m-quarter of 128). relu(x) = (x+|x|)/2:
//   phase A: acc = sum_m |A+C| over quarter; sat = sum_m A (ng==0 waves only)
//   phase B: combine quarters via LDS -> S[8][256] = 0.5*(sat + 512C + acc)
//   phase C: out = S*W2 + 512*b2 (k-quartered, LDS reduce)
// ---------------------------------------------------------------------------
__global__ __launch_bounds__(1024) void fused_main(
    const float* __restrict__ A, const float* __restrict__ C,
    const float* __restrict__ W2, const float* __restrict__ b2,
    float* __restrict__ out)
{
    __shared__ __align__(16) float Spart[3][8][HH];  // 24 KB (aliased by red)
    __shared__ __align__(16) float SsatL[4][HH];     // 4 KB
    __shared__ __align__(16) float S[8][HH];         // 8 KB
    const int bid = blockIdx.x;
    const int b   = bid >> 6;
    const int n0  = (bid & 63) * 8;
    const int t   = threadIdx.x;

    // ---- phase A ----
    const int hq = t & 63, h0 = hq * 4;
    const int ng = (t >> 6) & 3;                 // wave-uniform: rows n0+2ng,+1
    const int qm = t >> 8;                       // wave-uniform m-quarter

    const float* Crow = C + ((size_t)(b * NN + n0 + ng * 2)) * HH + h0;
    const v4f c0 = *reinterpret_cast<const v4f*>(&Crow[0]);
    const v4f c1 = *reinterpret_cast<const v4f*>(&Crow[HH]);
    v4f acc0 = (v4f){0.f,0.f,0.f,0.f}, acc1 = acc0, sat = acc0;

    const float* Ab = A + ((size_t)(b * MM + qm * 128)) * HH + h0;
    if (ng == 0) {
#pragma unroll 8
        for (int m = 0; m < 128; ++m) {
            const v4f a = *reinterpret_cast<const v4f*>(&Ab[(size_t)m * HH]);
            sat += a;
            const v4f s0 = a + c0;
            const v4f s1 = a + c1;
            acc0.x += fabsf(s0.x); acc0.y += fabsf(s0.y);
            acc0.z += fabsf(s0.z); acc0.w += fabsf(s0.w);
            acc1.x += fabsf(s1.x); acc1.y += fabsf(s1.y);
            acc1.z += fabsf(s1.z); acc1.w += fabsf(s1.w);
        }
    } else {
#pragma unroll 8
        for (int m = 0; m < 128; ++m) {
            const v4f a = *reinterpret_cast<const v4f*>(&Ab[(size_t)m * HH]);
            const v4f s0 = a + c0;
            const v4f s1 = a + c1;
            acc0.x += fabsf(s0.x); acc0.y += fabsf(s0.y);
            acc0.z += fabsf(s0.z); acc0.w += fabsf(s0.w);
            acc1.x += fabsf(s1.x); acc1.y += fabsf(s1.y);
            acc1.z += fabsf(s1.z); acc1.w += fabsf(s1.w);
        }
    }

    // ---- phase B: combine m-quarters ----
    if (qm) {
        *reinterpret_cast<v4f*>(&Spart[qm - 1][ng * 2 + 0][h0]) = acc0;
        *reinterpret_cast<v4f*>(&Spart[qm - 1][ng * 2 + 1][h0]) = acc1;
    }
    if (ng == 0)
        *reinterpret_cast<v4f*>(&SsatL[qm][h0]) = sat;
    __syncthreads();

    if (qm == 0) {
        v4f st = *reinterpret_cast<const v4f*>(&SsatL[0][h0]);
#pragma unroll
        for (int i = 1; i < 4; ++i)
            st += *reinterpret_cast<const v4f*>(&SsatL[i][h0]);
        v4f a0 = acc0, a1 = acc1;
#pragma unroll
        for (int p = 0; p < 3; ++p) {
            a0 += *reinterpret_cast<const v4f*>(&Spart[p][ng * 2 + 0][h0]);
            a1 += *reinterpret_cast<const v4f*>(&Spart[p][ng * 2 + 1][h0]);
        }
        *reinterpret_cast<v4f*>(&S[ng * 2 + 0][h0]) = 0.5f * (st + 512.f * c0 + a0);
        *reinterpret_cast<v4f*>(&S[ng * 2 + 1][h0]) = 0.5f * (st + 512.f * c1 + a1);
    }
    __syncthreads();

    // ---- phase C: out = S*W2 + 512*b2, k split 4 ways ----
    const int o0 = (t & 31) * 4;
    const int r  = (t >> 5) & 7;
    const int kq = t >> 8;                        // wave-uniform k-quarter
    const int k0 = kq * 64;

    v4f a4 = (v4f){0.f, 0.f, 0.f, 0.f};
    const float* w2p = W2 + o0;
#pragma unroll 4
    for (int k = k0; k < k0 + 64; k += 4) {
        const v4f sv = *reinterpret_cast<const v4f*>(&S[r][k]);       // broadcast
        const v4f wA = *reinterpret_cast<const v4f*>(&w2p[(k + 0) * DOUTC]);
        const v4f wB = *reinterpret_cast<const v4f*>(&w2p[(k + 1) * DOUTC]);
        const v4f wC = *reinterpret_cast<const v4f*>(&w2p[(k + 2) * DOUTC]);
        const v4f wD = *reinterpret_cast<const v4f*>(&w2p[(k + 3) * DOUTC]);
        a4 += wA * sv.x;
        a4 += wB * sv.y;
        a4 += wC * sv.z;
        a4 += wD * sv.w;
    }

    v4f* red = reinterpret_cast<v4f*>(&Spart[0][0][0]);   // 12 KB of the 24 KB
    if (kq) red[(kq - 1) * 256 + (t & 255)] = a4;
    __syncthreads();
    if (kq == 0) {
#pragma unroll
        for (int p = 0; p < 3; ++p) a4 += red[p * 256 + t];
        a4 += 512.f * (*reinterpret_cast<const v4f*>(&b2[o0]));
        *reinterpret_cast<v4f*>(&out[((size_t)(b * NN + n0 + r)) * DOUTC + o0]) = a4;
    }
}

// ---------------------------------------------------------------------------
extern "C" void kernel_launch(void* const* d_in, const int* in_sizes, int n_in,
                              void* d_out, int out_size, void* d_ws, size_t ws_size,
                              hipStream_t stream) {
    const float* X  = (const float*)d_in[0];
    const float* Y  = (const float*)d_in[1];
    const float* W1 = (const float*)d_in[2];
    const float* b1 = (const float*)d_in[3];
    const float* W2 = (const float*)d_in[4];
    const float* b2 = (const float*)d_in[5];
    float* out = (float*)d_out;

    float* AC = (float*)d_ws;        // 4 MB: A rows 0..2047, C rows 2048..4095
    float* A  = AC;
    float* Cm = AC + 2048 * HH;

    hipLaunchKernelGGL(precompute_ac, dim3(256), dim3(1024), 0, stream,
                       X, Y, W1, b1, AC);
    hipLaunchKernelGGL(fused_main, dim3(256), dim3(1024), 0, stream,
                       A, Cm, W2, b2, out);
}